// Round 3
// baseline (2980.079 us; speedup 1.0000x reference)
//
#include <hip/hip_runtime.h>
#include <math.h>

// ---------------------------------------------------------------------------
// Invariant Point Attention (AF2-style), B=1, N=768, C1=384, C2=128, H=12,
// SQK=SV=16, PQK=4, PV=8.  f32, flash attention split over 4 j-chunks,
// per-wave-private softmax (wave w owns heads 3w..3w+2).
// ---------------------------------------------------------------------------

namespace {
constexpr int NRES = 768;
constexpr int C1V  = 384;

// workspace layout (float offsets)
constexpr size_t OFF_R     = 0;         // [768][12]  rotation (9 used)
constexpr size_t OFF_T     = 10240;     // [768][4]   translation (3 used)
constexpr size_t OFF_PW    = 13824;     // [16]       head point weights
constexpr size_t OFF_W2DT  = 13952;     // [12][128]  w2d transposed
constexpr size_t OFF_WPACK = 16384;     // [384][1152] packed proj weights
constexpr size_t OFF_BPACK = 458752;    // [1152]     packed proj bias
constexpr size_t OFF_PROJ  = 460800;    // [768][1152] proj result:
                                        //   +0 qs(192) | +192 kv(384) | +576 qp(144) | +720 kvp(432)
constexpr size_t OFF_QPT   = 1345536;   // [768][12][4][3]  q points (global frame)
constexpr size_t OFF_KPT   = 1456128;   // [768][12][4][3]  k points (global frame)
constexpr size_t OFF_VPTT  = 1566720;   // [12*8*3][768]    v points transposed
constexpr size_t OFF_VST   = 1787904;   // [12*16][768]     v scalar transposed
constexpr size_t OFF_FA    = 1935360;   // [768][2112] final_act
constexpr size_t OFF_PARTIAL = 3557376; // [768][4][2048] flash partials:
                                        //   [0..12) m | [12..24) s | [24..1560) acc2d 12x128
                                        //   [1560..1752) scalar 12x16 | [1752..2040) point 12x24
constexpr size_t OFF_PART  = 3557376;   // k7 split-K partials alias PARTIAL (comb done first)
}

// ---------------- K0: rotations, translations, pw, w2d transpose ------------
__global__ void k0_prep(const float* __restrict__ recT,
                        const float* __restrict__ tw,
                        const float* __restrict__ w2d,
                        float* __restrict__ ws) {
  int gid = blockIdx.x * 256 + threadIdx.x;
  if (gid < NRES) {
    float w = recT[gid*7+0], x = recT[gid*7+1], y = recT[gid*7+2], z = recT[gid*7+3];
    float inv = rsqrtf(w*w + x*x + y*y + z*z);
    w *= inv; x *= inv; y *= inv; z *= inv;
    float* r = ws + OFF_R + (size_t)gid*12;
    r[0] = 1.f-2.f*(y*y+z*z); r[1] = 2.f*(x*y-w*z);     r[2] = 2.f*(x*z+w*y);
    r[3] = 2.f*(x*y+w*z);     r[4] = 1.f-2.f*(x*x+z*z); r[5] = 2.f*(y*z-w*x);
    r[6] = 2.f*(x*z-w*y);     r[7] = 2.f*(y*z+w*x);     r[8] = 1.f-2.f*(x*x+y*y);
    float* tv = ws + OFF_T + (size_t)gid*4;
    tv[0] = recT[gid*7+4]; tv[1] = recT[gid*7+5]; tv[2] = recT[gid*7+6]; tv[3] = 0.f;
  } else if (gid < NRES + 12) {
    int h = gid - NRES;
    (ws + OFF_PW)[h] = sqrtf(1.f/54.f) * log1pf(expf(tw[h]));   // pw*softplus
  } else if (gid < NRES + 12 + 1536) {
    int idx = gid - NRES - 12;
    int h = idx % 12, c = idx / 12;
    (ws + OFF_W2DT)[h*128 + c] = w2d[c*12 + h];
  }
}

// ---------------- K0b: pack the 4 weight matrices + biases ------------------
__global__ void k0b_pack(const float* __restrict__ qw,  const float* __restrict__ qb,
                         const float* __restrict__ kvw, const float* __restrict__ kvb,
                         const float* __restrict__ qpw, const float* __restrict__ qpb,
                         const float* __restrict__ kvpw,const float* __restrict__ kvpb,
                         float* __restrict__ ws) {
  int idx = blockIdx.x * 256 + threadIdx.x;
  if (idx < 384*1152) {
    int k = idx / 1152, col = idx % 1152;
    float v;
    if (col < 192)      v = qw[(size_t)k*192 + col];
    else if (col < 576) v = kvw[(size_t)k*384 + (col-192)];
    else if (col < 720) v = qpw[(size_t)k*144 + (col-576)];
    else                v = kvpw[(size_t)k*432 + (col-720)];
    (ws + OFF_WPACK)[idx] = v;
  } else if (idx < 384*1152 + 1152) {
    int col = idx - 384*1152;
    float v;
    if (col < 192)      v = qb[col];
    else if (col < 576) v = kvb[col-192];
    else if (col < 720) v = qpb[col-576];
    else                v = kvpb[col-720];
    (ws + OFF_BPACK)[col] = v;
  }
}

// ---------------- K1: tiled projection GEMM 768x384 @ 384x1152 + bias -------
__global__ __launch_bounds__(256) void k1_proj(const float* __restrict__ x,
                                               float* __restrict__ ws) {
  int bi = blockIdx.x, bo = blockIdx.y, t = threadIdx.x;
  __shared__ float AsT[16*68];
  __shared__ float Bs[16*68];
  const float* W = ws + OFF_WPACK;
  float accv[4][4] = {};
  int i0 = bi*64, o0 = bo*64;
  int ti = t >> 4, to = t & 15;
  for (int kt = 0; kt < 24; kt++) {
    int k0 = kt*16;
    {
      int r = t >> 2, kq = t & 3;
      float4 a = *(const float4*)(x + (size_t)(i0+r)*C1V + k0 + kq*4);
      AsT[(kq*4+0)*68 + r] = a.x;
      AsT[(kq*4+1)*68 + r] = a.y;
      AsT[(kq*4+2)*68 + r] = a.z;
      AsT[(kq*4+3)*68 + r] = a.w;
      int kr = t >> 4, ol = t & 15;
      *(float4*)&Bs[kr*68 + ol*4] =
          *(const float4*)(W + (size_t)(k0+kr)*1152 + o0 + ol*4);
    }
    __syncthreads();
    for (int k = 0; k < 16; k++) {
      float4 a4 = *(float4*)&AsT[k*68 + ti*4];
      float4 b4 = *(float4*)&Bs[k*68 + to*4];
      accv[0][0] += a4.x*b4.x; accv[0][1] += a4.x*b4.y; accv[0][2] += a4.x*b4.z; accv[0][3] += a4.x*b4.w;
      accv[1][0] += a4.y*b4.x; accv[1][1] += a4.y*b4.y; accv[1][2] += a4.y*b4.z; accv[1][3] += a4.y*b4.w;
      accv[2][0] += a4.z*b4.x; accv[2][1] += a4.z*b4.y; accv[2][2] += a4.z*b4.z; accv[2][3] += a4.z*b4.w;
      accv[3][0] += a4.w*b4.x; accv[3][1] += a4.w*b4.y; accv[3][2] += a4.w*b4.z; accv[3][3] += a4.w*b4.w;
    }
    __syncthreads();
  }
  float* proj = ws + OFF_PROJ;
  const float* bp = ws + OFF_BPACK;
  #pragma unroll
  for (int ii = 0; ii < 4; ii++) {
    int orow = i0 + ti*4 + ii;
    int ocol = o0 + to*4;
    float4 bv = *(const float4*)(bp + ocol);
    float4 v = make_float4(accv[ii][0]+bv.x, accv[ii][1]+bv.y,
                           accv[ii][2]+bv.z, accv[ii][3]+bv.w);
    *(float4*)&proj[(size_t)orow*1152 + ocol] = v;
  }
}

// ---------------- K2: apply frames, build transposed V layouts --------------
__global__ __launch_bounds__(256) void k2_frames(float* __restrict__ ws) {
  int i = blockIdx.x, t = threadIdx.x;
  const float* R  = ws + OFF_R + (size_t)i*12;
  const float* tv = ws + OFF_T + (size_t)i*4;
  const float* prow = ws + OFF_PROJ + (size_t)i*1152;
  if (t < 144) {  // q points: d in [0,48), ci in [0,3)
    int d = t % 48, ci = t / 48;
    const float* qp = prow + 576;
    float v = R[ci*3+0]*qp[0*48+d] + R[ci*3+1]*qp[1*48+d] + R[ci*3+2]*qp[2*48+d] + tv[ci];
    int h = d / 4, p = d % 4;
    (ws + OFF_QPT)[(size_t)i*144 + h*12 + p*3 + ci] = v;
  }
  for (int r = 0; r < 2; r++) {  // kv points: 432 items
    int item = t + r*256;
    if (item < 432) {
      int d = item % 144, ci = item / 144;
      const float* kp = prow + 720;
      float v = R[ci*3+0]*kp[0*144+d] + R[ci*3+1]*kp[1*144+d] + R[ci*3+2]*kp[2*144+d] + tv[ci];
      int h = d / 12, pp = d % 12;
      if (pp < 4)
        (ws + OFF_KPT)[(size_t)i*144 + h*12 + pp*3 + ci] = v;
      else
        (ws + OFF_VPTT)[((size_t)(h*8 + (pp-4))*3 + ci)*768 + i] = v;
    }
  }
  if (t < 192) {  // v scalar transpose: [h*16+s][768]
    int h = t / 16, s = t % 16;
    (ws + OFF_VST)[(size_t)t*768 + i] = prow[192 + h*32 + 16 + s];
  }
}

// ---------------- K_att2: flash attention, (i, j-chunk) blocks --------------
// Wave w privately owns heads 3w..3w+2: logits, softmax state (registers),
// att2d accumulate, and V slots.  Only the rep tile is cross-wave (2 barriers).
__global__ __launch_bounds__(256, 3) void k_att2(const float* __restrict__ rep,
                                                 const float* __restrict__ w2db_,
                                                 float* __restrict__ ws) {
  __shared__ float tile[64*132];   // rep tile [jl][c], padded stride 132
  __shared__ float ptile[12*68];   // p values [h][jl], stride 68 (bank-spread)
  __shared__ float wds[12*128];    // w2d^T
  __shared__ float qsl[192], qptl[144];

  int jc = blockIdx.x, i = blockIdx.y, t = threadIdx.x;
  int w = t >> 6, lane = t & 63;
  int hb = w*3;

  // ---- init ----
  for (int u = t; u < 1536; u += 256) wds[u] = (ws + OFF_W2DT)[u];
  if (t < 192) qsl[t]  = (ws + OFF_PROJ)[(size_t)i*1152 + t];
  if (t < 144) qptl[t] = (ws + OFF_QPT)[(size_t)i*144 + t];
  float pwv[3], w2dbv[3];
  #pragma unroll
  for (int hh = 0; hh < 3; hh++) {
    pwv[hh]   = (ws + OFF_PW)[hb+hh];
    w2dbv[hh] = w2db_[hb+hh];
  }
  float m0 = -1e30f, m1 = -1e30f, m2 = -1e30f;
  float s0 = 0.f, s1 = 0.f, s2 = 0.f;
  float a2d0[2] = {0.f,0.f}, a2d1[2] = {0.f,0.f}, a2d2[2] = {0.f,0.f};

  // V slots: slot0 = lane (all valid), slot1 = lane+64 (valid if <120)
  int hh0 = (lane < 40) ? 0 : 1;
  int idx0 = lane - hh0*40;
  const float* vrow0 = (idx0 < 16)
      ? ws + OFF_VST  + (size_t)((hb+hh0)*16 + idx0)*768
      : ws + OFF_VPTT + (size_t)((hb+hh0)*24 + idx0-16)*768;
  int pr0 = (hb+hh0)*68;
  int s1i = lane + 64;
  bool has1 = s1i < 120;
  int hh1 = (s1i < 80) ? 1 : 2;
  int idx1 = s1i - hh1*40;
  const float* vrow1 = (idx1 < 16)
      ? ws + OFF_VST  + (size_t)((hb+hh1)*16 + idx1)*768
      : ws + OFF_VPTT + (size_t)((hb+hh1)*24 + idx1-16)*768;
  int pr1 = (hb+hh1)*68;
  float accV0 = 0.f, accV1 = 0.f;

  const float sw  = 0.14433756729740643f;   // sqrt(1/48)
  const float c2d = 0.5773502691896258f;    // sqrt(1/3)

  for (int tt = 0; tt < 3; tt++) {
    int j0 = jc*192 + tt*64;
    // ---- stage rep tile (all waves) ----
    #pragma unroll
    for (int k = 0; k < 8; k++) {
      int u = t + k*256;
      int row = u >> 5, c4 = u & 31;
      *(float4*)&tile[row*132 + c4*4] =
          *(const float4*)&rep[((size_t)i*768 + (j0+row))*128 + c4*4];
    }
    __syncthreads();

    // ---- logits for heads hb..hb+2, j = j0+lane ----
    float a2d[3] = {0.f, 0.f, 0.f};
    for (int c4 = 0; c4 < 32; c4++) {
      float4 v = *(float4*)&tile[lane*132 + c4*4];
      #pragma unroll
      for (int hh = 0; hh < 3; hh++) {
        float4 wv = *(float4*)&wds[(hb+hh)*128 + c4*4];
        a2d[hh] += v.x*wv.x + v.y*wv.y + v.z*wv.z + v.w*wv.w;
      }
    }
    int j = j0 + lane;
    const float* ksr  = ws + OFF_PROJ + (size_t)j*1152 + 192;
    const float* kptr = ws + OFF_KPT + (size_t)j*144;
    float l[3];
    #pragma unroll
    for (int hh = 0; hh < 3; hh++) {
      int h = hb + hh;
      float ds_ = 0.f;
      #pragma unroll
      for (int s4 = 0; s4 < 4; s4++) {
        float4 q4 = *(const float4*)(qsl + h*16 + s4*4);
        float4 k4 = *(const float4*)(ksr + h*32 + s4*4);
        ds_ += q4.x*k4.x + q4.y*k4.y + q4.z*k4.z + q4.w*k4.w;
      }
      float dp = 0.f;
      #pragma unroll
      for (int pc = 0; pc < 3; pc++) {
        float4 q4 = *(const float4*)(qptl + h*12 + pc*4);
        float4 k4 = *(const float4*)(kptr + h*12 + pc*4);
        float dx = q4.x-k4.x, dy = q4.y-k4.y, dz = q4.z-k4.z, dw = q4.w-k4.w;
        dp += dx*dx + dy*dy + dz*dz + dw*dw;
      }
      l[hh] = sw*ds_ - 0.5f*pwv[hh]*dp + c2d*(a2d[hh] + w2dbv[hh]);
    }

    // ---- per-wave online softmax (registers; lane-uniform after reduce) ----
    float f0, f1, f2;
    {
      float mt = l[0];
      #pragma unroll
      for (int d = 1; d < 64; d <<= 1) mt = fmaxf(mt, __shfl_xor(mt, d));
      float mn = fmaxf(m0, mt); f0 = __expf(m0 - mn); m0 = mn;
      float p = __expf(l[0] - mn); ptile[(hb+0)*68 + lane] = p;
      float ss = p;
      #pragma unroll
      for (int d = 1; d < 64; d <<= 1) ss += __shfl_xor(ss, d);
      s0 = s0*f0 + ss;
    }
    {
      float mt = l[1];
      #pragma unroll
      for (int d = 1; d < 64; d <<= 1) mt = fmaxf(mt, __shfl_xor(mt, d));
      float mn = fmaxf(m1, mt); f1 = __expf(m1 - mn); m1 = mn;
      float p = __expf(l[1] - mn); ptile[(hb+1)*68 + lane] = p;
      float ss = p;
      #pragma unroll
      for (int d = 1; d < 64; d <<= 1) ss += __shfl_xor(ss, d);
      s1 = s1*f1 + ss;
    }
    {
      float mt = l[2];
      #pragma unroll
      for (int d = 1; d < 64; d <<= 1) mt = fmaxf(mt, __shfl_xor(mt, d));
      float mn = fmaxf(m2, mt); f2 = __expf(m2 - mn); m2 = mn;
      float p = __expf(l[2] - mn); ptile[(hb+2)*68 + lane] = p;
      float ss = p;
      #pragma unroll
      for (int d = 1; d < 64; d <<= 1) ss += __shfl_xor(ss, d);
      s2 = s2*f2 + ss;
    }

    // ---- att2d accumulate: lane owns c-pair, own 3 heads, all 64 j --------
    a2d0[0] *= f0; a2d0[1] *= f0;
    a2d1[0] *= f1; a2d1[1] *= f1;
    a2d2[0] *= f2; a2d2[1] *= f2;
    for (int jq = 0; jq < 16; jq++) {
      float4 p0 = *(float4*)&ptile[(hb+0)*68 + jq*4];
      float4 p1 = *(float4*)&ptile[(hb+1)*68 + jq*4];
      float4 p2 = *(float4*)&ptile[(hb+2)*68 + jq*4];
      #pragma unroll
      for (int r = 0; r < 4; r++) {
        float2 r2 = *(float2*)&tile[(jq*4+r)*132 + lane*2];
        float pa = (r==0)?p0.x:(r==1)?p0.y:(r==2)?p0.z:p0.w;
        float pb = (r==0)?p1.x:(r==1)?p1.y:(r==2)?p1.z:p1.w;
        float pc = (r==0)?p2.x:(r==1)?p2.y:(r==2)?p2.z:p2.w;
        a2d0[0] += pa*r2.x; a2d0[1] += pa*r2.y;
        a2d1[0] += pb*r2.x; a2d1[1] += pb*r2.y;
        a2d2[0] += pc*r2.x; a2d2[1] += pc*r2.y;
      }
    }

    // ---- V slots ----
    {
      float fsel = (lane < 40) ? f0 : f1;
      float a = accV0 * fsel;
      const float* vr = vrow0 + j0;
      for (int q = 0; q < 16; q++) {
        float4 v4 = *(const float4*)(vr + q*4);
        float4 p4 = *(float4*)&ptile[pr0 + q*4];
        a += p4.x*v4.x + p4.y*v4.y + p4.z*v4.z + p4.w*v4.w;
      }
      accV0 = a;
    }
    if (has1) {
      float fsel = (s1i < 80) ? f1 : f2;
      float a = accV1 * fsel;
      const float* vr = vrow1 + j0;
      for (int q = 0; q < 16; q++) {
        float4 v4 = *(const float4*)(vr + q*4);
        float4 p4 = *(float4*)&ptile[pr1 + q*4];
        a += p4.x*v4.x + p4.y*v4.y + p4.z*v4.z + p4.w*v4.w;
      }
      accV1 = a;
    }
    __syncthreads();   // tile reused next iteration
  }

  // ---- epilogue: write per-(i,chunk) partials ----
  float* part = ws + OFF_PARTIAL + ((size_t)i*4 + jc)*2048;
  if (lane == 0) {
    part[hb+0] = m0; part[hb+1] = m1; part[hb+2] = m2;
    part[12+hb+0] = s0; part[12+hb+1] = s1; part[12+hb+2] = s2;
  }
  part[24 + (hb+0)*128 + lane*2 + 0] = a2d0[0];
  part[24 + (hb+0)*128 + lane*2 + 1] = a2d0[1];
  part[24 + (hb+1)*128 + lane*2 + 0] = a2d1[0];
  part[24 + (hb+1)*128 + lane*2 + 1] = a2d1[1];
  part[24 + (hb+2)*128 + lane*2 + 0] = a2d2[0];
  part[24 + (hb+2)*128 + lane*2 + 1] = a2d2[1];
  {
    int dst0 = (idx0 < 16) ? 1560 + (hb+hh0)*16 + idx0
                           : 1752 + (hb+hh0)*24 + (idx0-16);
    part[dst0] = accV0;
  }
  if (has1) {
    int dst1 = (idx1 < 16) ? 1560 + (hb+hh1)*16 + idx1
                           : 1752 + (hb+hh1)*24 + (idx1-16);
    part[dst1] = accV1;
  }
}

// ---------------- K_comb: combine 4 chunks, normalize, epilogue -------------
__global__ __launch_bounds__(256) void k_comb(float* __restrict__ ws) {
  int i = blockIdx.x, t = threadIdx.x;
  __shared__ float coef[4][12];
  __shared__ float respt[288];
  const float* P = ws + OFF_PARTIAL + (size_t)i*4*2048;
  if (t < 12) {
    float ma = P[t], mb = P[2048+t], mc = P[4096+t], md = P[6144+t];
    float M = fmaxf(fmaxf(ma,mb), fmaxf(mc,md));
    float ea = __expf(ma-M), eb = __expf(mb-M), ec = __expf(mc-M), ed = __expf(md-M);
    float S = P[12+t]*ea + P[2048+12+t]*eb + P[4096+12+t]*ec + P[6144+12+t]*ed;
    float inv = 1.f/S;
    coef[0][t] = ea*inv; coef[1][t] = eb*inv; coef[2][t] = ec*inv; coef[3][t] = ed*inv;
  }
  __syncthreads();
  float* fa = ws + OFF_FA + (size_t)i*2112;
  // att2d (1536)
  for (int r = 0; r < 6; r++) {
    int u = t + r*256;
    int h = u >> 7;
    fa[576+u] = P[24+u]*coef[0][h] + P[2048+24+u]*coef[1][h]
              + P[4096+24+u]*coef[2][h] + P[6144+24+u]*coef[3][h];
  }
  // scalar (192)
  if (t < 192) {
    int h = t >> 4;
    fa[t] = P[1560+t]*coef[0][h] + P[2048+1560+t]*coef[1][h]
          + P[4096+1560+t]*coef[2][h] + P[6144+1560+t]*coef[3][h];
  }
  // points (288) -> respt
  #pragma unroll
  for (int r = 0; r < 2; r++) {
    int u = t + r*256;
    if (u < 288) {
      int h = u / 24;
      respt[u] = P[1752+u]*coef[0][h] + P[2048+1752+u]*coef[1][h]
               + P[4096+1752+u]*coef[2][h] + P[6144+1752+u]*coef[3][h];
    }
  }
  __syncthreads();
  if (t < 96) {
    const float* R  = ws + OFF_R + (size_t)i*12;
    const float* tv = ws + OFF_T + (size_t)i*4;
    float g0 = respt[t*3+0] - tv[0];
    float g1 = respt[t*3+1] - tv[1];
    float g2 = respt[t*3+2] - tv[2];
    float l0 = R[0]*g0 + R[3]*g1 + R[6]*g2;   // R^T * g
    float l1 = R[1]*g0 + R[4]*g1 + R[7]*g2;
    float l2 = R[2]*g0 + R[5]*g1 + R[8]*g2;
    fa[192 + 0*96 + t] = l0;
    fa[192 + 1*96 + t] = l1;
    fa[192 + 2*96 + t] = l2;
    fa[480 + t] = sqrtf(1e-8f + l0*l0 + l1*l1 + l2*l2);
  }
}

// ---------------- K7: final GEMM 768x2112 @ 2112x384, split-K=4 -------------
__global__ __launch_bounds__(256) void k7_gemm(const float* __restrict__ finw,
                                               float* __restrict__ ws) {
  int bi = blockIdx.x, bo = blockIdx.y, bz = blockIdx.z, t = threadIdx.x;
  __shared__ float AsT[16*68];
  __shared__ float Bs[16*68];
  const float* fa = ws + OFF_FA;
  float accv[4][4] = {};
  int i0 = bi*64, o0 = bo*64;
  int ti = t >> 4, to = t & 15;
  for (int kt = 0; kt < 33; kt++) {
    int k0 = bz*528 + kt*16;
    {
      int r = t >> 2, kq = t & 3;
      float4 a = *(const float4*)(fa + (size_t)(i0+r)*2112 + k0 + kq*4);
      AsT[(kq*4+0)*68 + r] = a.x;
      AsT[(kq*4+1)*68 + r] = a.y;
      AsT[(kq*4+2)*68 + r] = a.z;
      AsT[(kq*4+3)*68 + r] = a.w;
      int kr = t >> 4, ol = t & 15;
      *(float4*)&Bs[kr*68 + ol*4] =
          *(const float4*)(finw + (size_t)(k0+kr)*384 + o0 + ol*4);
    }
    __syncthreads();
    for (int k = 0; k < 16; k++) {
      float4 a4 = *(float4*)&AsT[k*68 + ti*4];
      float4 b4 = *(float4*)&Bs[k*68 + to*4];
      accv[0][0] += a4.x*b4.x; accv[0][1] += a4.x*b4.y; accv[0][2] += a4.x*b4.z; accv[0][3] += a4.x*b4.w;
      accv[1][0] += a4.y*b4.x; accv[1][1] += a4.y*b4.y; accv[1][2] += a4.y*b4.z; accv[1][3] += a4.y*b4.w;
      accv[2][0] += a4.z*b4.x; accv[2][1] += a4.z*b4.y; accv[2][2] += a4.z*b4.z; accv[2][3] += a4.z*b4.w;
      accv[3][0] += a4.w*b4.x; accv[3][1] += a4.w*b4.y; accv[3][2] += a4.w*b4.z; accv[3][3] += a4.w*b4.w;
    }
    __syncthreads();
  }
  float* part = ws + OFF_PART + (size_t)bz*768*384;
  #pragma unroll
  for (int ii = 0; ii < 4; ii++) {
    float4 v = make_float4(accv[ii][0], accv[ii][1], accv[ii][2], accv[ii][3]);
    *(float4*)&part[(size_t)(i0 + ti*4 + ii)*384 + o0 + to*4] = v;
  }
}

// ---------------- K8: split-K reduce + bias ---------------------------------
__global__ void k8_out(const float* __restrict__ finb,
                       const float* __restrict__ ws,
                       float* __restrict__ out) {
  int idx = blockIdx.x*256 + threadIdx.x;  // 294912
  int o = idx % 384;
  const float* part = ws + OFF_PART;
  out[idx] = part[idx] + part[294912 + idx] + part[2*294912 + idx]
           + part[3*294912 + idx] + finb[o];
}

// ---------------------------------------------------------------------------
extern "C" void kernel_launch(void* const* d_in, const int* in_sizes, int n_in,
                              void* d_out, int out_size, void* d_ws, size_t ws_size,
                              hipStream_t stream) {
  const float* rec1d = (const float*)d_in[0];
  const float* rep2d = (const float*)d_in[1];
  const float* recT  = (const float*)d_in[2];
  const float* qw    = (const float*)d_in[3];
  const float* qb    = (const float*)d_in[4];
  const float* kvw   = (const float*)d_in[5];
  const float* kvb   = (const float*)d_in[6];
  const float* qpw   = (const float*)d_in[7];
  const float* qpb   = (const float*)d_in[8];
  const float* kvpw  = (const float*)d_in[9];
  const float* kvpb  = (const float*)d_in[10];
  const float* w2dw  = (const float*)d_in[11];
  const float* w2db  = (const float*)d_in[12];
  const float* finw  = (const float*)d_in[13];
  const float* finb  = (const float*)d_in[14];
  const float* tw    = (const float*)d_in[15];
  float* ws  = (float*)d_ws;
  float* out = (float*)d_out;

  hipLaunchKernelGGL(k0_prep, dim3(10), dim3(256), 0, stream, recT, tw, w2dw, ws);
  hipLaunchKernelGGL(k0b_pack, dim3(1733), dim3(256), 0, stream,
                     qw, qb, kvw, kvb, qpw, qpb, kvpw, kvpb, ws);
  hipLaunchKernelGGL(k1_proj, dim3(12, 18), dim3(256), 0, stream, rec1d, ws);
  hipLaunchKernelGGL(k2_frames, dim3(768), dim3(256), 0, stream, ws);
  hipLaunchKernelGGL(k_att2, dim3(4, 768), dim3(256), 0, stream, rep2d, w2db, ws);
  hipLaunchKernelGGL(k_comb, dim3(768), dim3(256), 0, stream, ws);
  hipLaunchKernelGGL(k7_gemm, dim3(12, 6, 4), dim3(256), 0, stream, finw, ws);
  hipLaunchKernelGGL(k8_out, dim3(1152), dim3(256), 0, stream, finb, ws, out);
}

// Round 5
// 1027.366 us; speedup vs baseline: 2.9007x; 2.9007x over previous
//
#include <hip/hip_runtime.h>
#include <math.h>

// ---------------------------------------------------------------------------
// Invariant Point Attention (AF2-style), B=1, N=768, C1=384, C2=128, H=12,
// SQK=SV=16, PQK=4, PV=8.  f32, flash attention split over 4 j-chunks,
// per-wave-private softmax (wave w owns heads 3w..3w+2).
//
// R3 lesson: __launch_bounds__(256,3) capped VGPRs at 84 -> massive scratch
// spill (4.9 GB WRITE_SIZE, 8 GB HBM traffic, VALUBusy 3.5%).  Occupancy is
// LDS-limited (44.5 KB -> 3 blocks/CU) anyway, so no min-waves hint.
// (R4 = identical resubmit; R3's fix never got benched due to GPU timeout.)
// ---------------------------------------------------------------------------

namespace {
constexpr int NRES = 768;
constexpr int C1V  = 384;

// workspace layout (float offsets)
constexpr size_t OFF_R     = 0;         // [768][12]  rotation (9 used)
constexpr size_t OFF_T     = 10240;     // [768][4]   translation (3 used)
constexpr size_t OFF_PW    = 13824;     // [16]       head point weights
constexpr size_t OFF_W2DT  = 13952;     // [12][128]  w2d transposed
constexpr size_t OFF_WPACK = 16384;     // [384][1152] packed proj weights
constexpr size_t OFF_BPACK = 458752;    // [1152]     packed proj bias
constexpr size_t OFF_PROJ  = 460800;    // [768][1152] proj result:
                                        //   +0 qs(192) | +192 kv(384) | +576 qp(144) | +720 kvp(432)
constexpr size_t OFF_QPT   = 1345536;   // [768][12][4][3]  q points (global frame)
constexpr size_t OFF_KPT   = 1456128;   // [768][12][4][3]  k points (global frame)
constexpr size_t OFF_VPTT  = 1566720;   // [12*8*3][768]    v points transposed
constexpr size_t OFF_VST   = 1787904;   // [12*16][768]     v scalar transposed
constexpr size_t OFF_FA    = 1935360;   // [768][2112] final_act
constexpr size_t OFF_PARTIAL = 3557376; // [768][4][2048] flash partials:
                                        //   [0..12) m | [12..24) s | [24..1560) acc2d 12x128
                                        //   [1560..1752) scalar 12x16 | [1752..2040) point 12x24
constexpr size_t OFF_PART  = 3557376;   // k7 split-K partials alias PARTIAL (comb done first)
}

// ---------------- K0: rotations, translations, pw, w2d transpose ------------
__global__ void k0_prep(const float* __restrict__ recT,
                        const float* __restrict__ tw,
                        const float* __restrict__ w2d,
                        float* __restrict__ ws) {
  int gid = blockIdx.x * 256 + threadIdx.x;
  if (gid < NRES) {
    float w = recT[gid*7+0], x = recT[gid*7+1], y = recT[gid*7+2], z = recT[gid*7+3];
    float inv = rsqrtf(w*w + x*x + y*y + z*z);
    w *= inv; x *= inv; y *= inv; z *= inv;
    float* r = ws + OFF_R + (size_t)gid*12;
    r[0] = 1.f-2.f*(y*y+z*z); r[1] = 2.f*(x*y-w*z);     r[2] = 2.f*(x*z+w*y);
    r[3] = 2.f*(x*y+w*z);     r[4] = 1.f-2.f*(x*x+z*z); r[5] = 2.f*(y*z-w*x);
    r[6] = 2.f*(x*z-w*y);     r[7] = 2.f*(y*z+w*x);     r[8] = 1.f-2.f*(x*x+y*y);
    float* tv = ws + OFF_T + (size_t)gid*4;
    tv[0] = recT[gid*7+4]; tv[1] = recT[gid*7+5]; tv[2] = recT[gid*7+6]; tv[3] = 0.f;
  } else if (gid < NRES + 12) {
    int h = gid - NRES;
    (ws + OFF_PW)[h] = sqrtf(1.f/54.f) * log1pf(expf(tw[h]));   // pw*softplus
  } else if (gid < NRES + 12 + 1536) {
    int idx = gid - NRES - 12;
    int h = idx % 12, c = idx / 12;
    (ws + OFF_W2DT)[h*128 + c] = w2d[c*12 + h];
  }
}

// ---------------- K0b: pack the 4 weight matrices + biases ------------------
__global__ void k0b_pack(const float* __restrict__ qw,  const float* __restrict__ qb,
                         const float* __restrict__ kvw, const float* __restrict__ kvb,
                         const float* __restrict__ qpw, const float* __restrict__ qpb,
                         const float* __restrict__ kvpw,const float* __restrict__ kvpb,
                         float* __restrict__ ws) {
  int idx = blockIdx.x * 256 + threadIdx.x;
  if (idx < 384*1152) {
    int k = idx / 1152, col = idx % 1152;
    float v;
    if (col < 192)      v = qw[(size_t)k*192 + col];
    else if (col < 576) v = kvw[(size_t)k*384 + (col-192)];
    else if (col < 720) v = qpw[(size_t)k*144 + (col-576)];
    else                v = kvpw[(size_t)k*432 + (col-720)];
    (ws + OFF_WPACK)[idx] = v;
  } else if (idx < 384*1152 + 1152) {
    int col = idx - 384*1152;
    float v;
    if (col < 192)      v = qb[col];
    else if (col < 576) v = kvb[col-192];
    else if (col < 720) v = qpb[col-576];
    else                v = kvpb[col-720];
    (ws + OFF_BPACK)[col] = v;
  }
}

// ---------------- K1: tiled projection GEMM 768x384 @ 384x1152 + bias -------
__global__ __launch_bounds__(256) void k1_proj(const float* __restrict__ x,
                                               float* __restrict__ ws) {
  int bi = blockIdx.x, bo = blockIdx.y, t = threadIdx.x;
  __shared__ float AsT[16*68];
  __shared__ float Bs[16*68];
  const float* W = ws + OFF_WPACK;
  float accv[4][4] = {};
  int i0 = bi*64, o0 = bo*64;
  int ti = t >> 4, to = t & 15;
  for (int kt = 0; kt < 24; kt++) {
    int k0 = kt*16;
    {
      int r = t >> 2, kq = t & 3;
      float4 a = *(const float4*)(x + (size_t)(i0+r)*C1V + k0 + kq*4);
      AsT[(kq*4+0)*68 + r] = a.x;
      AsT[(kq*4+1)*68 + r] = a.y;
      AsT[(kq*4+2)*68 + r] = a.z;
      AsT[(kq*4+3)*68 + r] = a.w;
      int kr = t >> 4, ol = t & 15;
      *(float4*)&Bs[kr*68 + ol*4] =
          *(const float4*)(W + (size_t)(k0+kr)*1152 + o0 + ol*4);
    }
    __syncthreads();
    for (int k = 0; k < 16; k++) {
      float4 a4 = *(float4*)&AsT[k*68 + ti*4];
      float4 b4 = *(float4*)&Bs[k*68 + to*4];
      accv[0][0] += a4.x*b4.x; accv[0][1] += a4.x*b4.y; accv[0][2] += a4.x*b4.z; accv[0][3] += a4.x*b4.w;
      accv[1][0] += a4.y*b4.x; accv[1][1] += a4.y*b4.y; accv[1][2] += a4.y*b4.z; accv[1][3] += a4.y*b4.w;
      accv[2][0] += a4.z*b4.x; accv[2][1] += a4.z*b4.y; accv[2][2] += a4.z*b4.z; accv[2][3] += a4.z*b4.w;
      accv[3][0] += a4.w*b4.x; accv[3][1] += a4.w*b4.y; accv[3][2] += a4.w*b4.z; accv[3][3] += a4.w*b4.w;
    }
    __syncthreads();
  }
  float* proj = ws + OFF_PROJ;
  const float* bp = ws + OFF_BPACK;
  #pragma unroll
  for (int ii = 0; ii < 4; ii++) {
    int orow = i0 + ti*4 + ii;
    int ocol = o0 + to*4;
    float4 bv = *(const float4*)(bp + ocol);
    float4 v = make_float4(accv[ii][0]+bv.x, accv[ii][1]+bv.y,
                           accv[ii][2]+bv.z, accv[ii][3]+bv.w);
    *(float4*)&proj[(size_t)orow*1152 + ocol] = v;
  }
}

// ---------------- K2: apply frames, build transposed V layouts --------------
__global__ __launch_bounds__(256) void k2_frames(float* __restrict__ ws) {
  int i = blockIdx.x, t = threadIdx.x;
  const float* R  = ws + OFF_R + (size_t)i*12;
  const float* tv = ws + OFF_T + (size_t)i*4;
  const float* prow = ws + OFF_PROJ + (size_t)i*1152;
  if (t < 144) {  // q points: d in [0,48), ci in [0,3)
    int d = t % 48, ci = t / 48;
    const float* qp = prow + 576;
    float v = R[ci*3+0]*qp[0*48+d] + R[ci*3+1]*qp[1*48+d] + R[ci*3+2]*qp[2*48+d] + tv[ci];
    int h = d / 4, p = d % 4;
    (ws + OFF_QPT)[(size_t)i*144 + h*12 + p*3 + ci] = v;
  }
  for (int r = 0; r < 2; r++) {  // kv points: 432 items
    int item = t + r*256;
    if (item < 432) {
      int d = item % 144, ci = item / 144;
      const float* kp = prow + 720;
      float v = R[ci*3+0]*kp[0*144+d] + R[ci*3+1]*kp[1*144+d] + R[ci*3+2]*kp[2*144+d] + tv[ci];
      int h = d / 12, pp = d % 12;
      if (pp < 4)
        (ws + OFF_KPT)[(size_t)i*144 + h*12 + pp*3 + ci] = v;
      else
        (ws + OFF_VPTT)[((size_t)(h*8 + (pp-4))*3 + ci)*768 + i] = v;
    }
  }
  if (t < 192) {  // v scalar transpose: [h*16+s][768]
    int h = t / 16, s = t % 16;
    (ws + OFF_VST)[(size_t)t*768 + i] = prow[192 + h*32 + 16 + s];
  }
}

// ---------------- K_att2: flash attention, (i, j-chunk) blocks --------------
// Wave w privately owns heads 3w..3w+2: logits, softmax state (registers),
// att2d accumulate, and V slots.  Only the rep tile is cross-wave (2 barriers).
// NOTE: no min-waves hint -- LDS caps occupancy at 3 blocks/CU; a VGPR cap
// here causes catastrophic scratch spill (R3: 84 VGPR -> 8 GB HBM traffic).
__global__ __launch_bounds__(256) void k_att2(const float* __restrict__ rep,
                                              const float* __restrict__ w2db_,
                                              float* __restrict__ ws) {
  __shared__ float tile[64*132];   // rep tile [jl][c], padded stride 132
  __shared__ float ptile[12*68];   // p values [h][jl], stride 68 (bank-spread)
  __shared__ float wds[12*128];    // w2d^T
  __shared__ float qsl[192], qptl[144];

  int jc = blockIdx.x, i = blockIdx.y, t = threadIdx.x;
  int w = t >> 6, lane = t & 63;
  int hb = w*3;

  // ---- init ----
  for (int u = t; u < 1536; u += 256) wds[u] = (ws + OFF_W2DT)[u];
  if (t < 192) qsl[t]  = (ws + OFF_PROJ)[(size_t)i*1152 + t];
  if (t < 144) qptl[t] = (ws + OFF_QPT)[(size_t)i*144 + t];
  float pwv[3], w2dbv[3];
  #pragma unroll
  for (int hh = 0; hh < 3; hh++) {
    pwv[hh]   = (ws + OFF_PW)[hb+hh];
    w2dbv[hh] = w2db_[hb+hh];
  }
  float m0 = -1e30f, m1 = -1e30f, m2 = -1e30f;
  float s0 = 0.f, s1 = 0.f, s2 = 0.f;
  float a2d0[2] = {0.f,0.f}, a2d1[2] = {0.f,0.f}, a2d2[2] = {0.f,0.f};

  // V slots: slot0 = lane (all valid), slot1 = lane+64 (valid if <120)
  int hh0 = (lane < 40) ? 0 : 1;
  int idx0 = lane - hh0*40;
  const float* vrow0 = (idx0 < 16)
      ? ws + OFF_VST  + (size_t)((hb+hh0)*16 + idx0)*768
      : ws + OFF_VPTT + (size_t)((hb+hh0)*24 + idx0-16)*768;
  int pr0 = (hb+hh0)*68;
  int s1i = lane + 64;
  bool has1 = s1i < 120;
  int hh1 = (s1i < 80) ? 1 : 2;
  int idx1 = s1i - hh1*40;
  const float* vrow1 = (idx1 < 16)
      ? ws + OFF_VST  + (size_t)((hb+hh1)*16 + idx1)*768
      : ws + OFF_VPTT + (size_t)((hb+hh1)*24 + idx1-16)*768;
  int pr1 = (hb+hh1)*68;
  float accV0 = 0.f, accV1 = 0.f;

  const float sw  = 0.14433756729740643f;   // sqrt(1/48)
  const float c2d = 0.5773502691896258f;    // sqrt(1/3)

  for (int tt = 0; tt < 3; tt++) {
    int j0 = jc*192 + tt*64;
    // ---- stage rep tile (all waves) ----
    #pragma unroll
    for (int k = 0; k < 8; k++) {
      int u = t + k*256;
      int row = u >> 5, c4 = u & 31;
      *(float4*)&tile[row*132 + c4*4] =
          *(const float4*)&rep[((size_t)i*768 + (j0+row))*128 + c4*4];
    }
    __syncthreads();

    // ---- logits for heads hb..hb+2, j = j0+lane ----
    float a2d[3] = {0.f, 0.f, 0.f};
    for (int c4 = 0; c4 < 32; c4++) {
      float4 v = *(float4*)&tile[lane*132 + c4*4];
      #pragma unroll
      for (int hh = 0; hh < 3; hh++) {
        float4 wv = *(float4*)&wds[(hb+hh)*128 + c4*4];
        a2d[hh] += v.x*wv.x + v.y*wv.y + v.z*wv.z + v.w*wv.w;
      }
    }
    int j = j0 + lane;
    const float* ksr  = ws + OFF_PROJ + (size_t)j*1152 + 192;
    const float* kptr = ws + OFF_KPT + (size_t)j*144;
    float l[3];
    #pragma unroll
    for (int hh = 0; hh < 3; hh++) {
      int h = hb + hh;
      float ds_ = 0.f;
      #pragma unroll
      for (int s4 = 0; s4 < 4; s4++) {
        float4 q4 = *(const float4*)(qsl + h*16 + s4*4);
        float4 k4 = *(const float4*)(ksr + h*32 + s4*4);
        ds_ += q4.x*k4.x + q4.y*k4.y + q4.z*k4.z + q4.w*k4.w;
      }
      float dp = 0.f;
      #pragma unroll
      for (int pc = 0; pc < 3; pc++) {
        float4 q4 = *(const float4*)(qptl + h*12 + pc*4);
        float4 k4 = *(const float4*)(kptr + h*12 + pc*4);
        float dx = q4.x-k4.x, dy = q4.y-k4.y, dz = q4.z-k4.z, dw = q4.w-k4.w;
        dp += dx*dx + dy*dy + dz*dz + dw*dw;
      }
      l[hh] = sw*ds_ - 0.5f*pwv[hh]*dp + c2d*(a2d[hh] + w2dbv[hh]);
    }

    // ---- per-wave online softmax (registers; lane-uniform after reduce) ----
    float f0, f1, f2;
    {
      float mt = l[0];
      #pragma unroll
      for (int d = 1; d < 64; d <<= 1) mt = fmaxf(mt, __shfl_xor(mt, d));
      float mn = fmaxf(m0, mt); f0 = __expf(m0 - mn); m0 = mn;
      float p = __expf(l[0] - mn); ptile[(hb+0)*68 + lane] = p;
      float ss = p;
      #pragma unroll
      for (int d = 1; d < 64; d <<= 1) ss += __shfl_xor(ss, d);
      s0 = s0*f0 + ss;
    }
    {
      float mt = l[1];
      #pragma unroll
      for (int d = 1; d < 64; d <<= 1) mt = fmaxf(mt, __shfl_xor(mt, d));
      float mn = fmaxf(m1, mt); f1 = __expf(m1 - mn); m1 = mn;
      float p = __expf(l[1] - mn); ptile[(hb+1)*68 + lane] = p;
      float ss = p;
      #pragma unroll
      for (int d = 1; d < 64; d <<= 1) ss += __shfl_xor(ss, d);
      s1 = s1*f1 + ss;
    }
    {
      float mt = l[2];
      #pragma unroll
      for (int d = 1; d < 64; d <<= 1) mt = fmaxf(mt, __shfl_xor(mt, d));
      float mn = fmaxf(m2, mt); f2 = __expf(m2 - mn); m2 = mn;
      float p = __expf(l[2] - mn); ptile[(hb+2)*68 + lane] = p;
      float ss = p;
      #pragma unroll
      for (int d = 1; d < 64; d <<= 1) ss += __shfl_xor(ss, d);
      s2 = s2*f2 + ss;
    }

    // ---- att2d accumulate: lane owns c-pair, own 3 heads, all 64 j --------
    a2d0[0] *= f0; a2d0[1] *= f0;
    a2d1[0] *= f1; a2d1[1] *= f1;
    a2d2[0] *= f2; a2d2[1] *= f2;
    for (int jq = 0; jq < 16; jq++) {
      float4 p0 = *(float4*)&ptile[(hb+0)*68 + jq*4];
      float4 p1 = *(float4*)&ptile[(hb+1)*68 + jq*4];
      float4 p2 = *(float4*)&ptile[(hb+2)*68 + jq*4];
      #pragma unroll
      for (int r = 0; r < 4; r++) {
        float2 r2 = *(float2*)&tile[(jq*4+r)*132 + lane*2];
        float pa = (r==0)?p0.x:(r==1)?p0.y:(r==2)?p0.z:p0.w;
        float pb = (r==0)?p1.x:(r==1)?p1.y:(r==2)?p1.z:p1.w;
        float pc = (r==0)?p2.x:(r==1)?p2.y:(r==2)?p2.z:p2.w;
        a2d0[0] += pa*r2.x; a2d0[1] += pa*r2.y;
        a2d1[0] += pb*r2.x; a2d1[1] += pb*r2.y;
        a2d2[0] += pc*r2.x; a2d2[1] += pc*r2.y;
      }
    }

    // ---- V slots ----
    {
      float fsel = (lane < 40) ? f0 : f1;
      float a = accV0 * fsel;
      const float* vr = vrow0 + j0;
      for (int q = 0; q < 16; q++) {
        float4 v4 = *(const float4*)(vr + q*4);
        float4 p4 = *(float4*)&ptile[pr0 + q*4];
        a += p4.x*v4.x + p4.y*v4.y + p4.z*v4.z + p4.w*v4.w;
      }
      accV0 = a;
    }
    if (has1) {
      float fsel = (s1i < 80) ? f1 : f2;
      float a = accV1 * fsel;
      const float* vr = vrow1 + j0;
      for (int q = 0; q < 16; q++) {
        float4 v4 = *(const float4*)(vr + q*4);
        float4 p4 = *(float4*)&ptile[pr1 + q*4];
        a += p4.x*v4.x + p4.y*v4.y + p4.z*v4.z + p4.w*v4.w;
      }
      accV1 = a;
    }
    __syncthreads();   // tile reused next iteration
  }

  // ---- epilogue: write per-(i,chunk) partials ----
  float* part = ws + OFF_PARTIAL + ((size_t)i*4 + jc)*2048;
  if (lane == 0) {
    part[hb+0] = m0; part[hb+1] = m1; part[hb+2] = m2;
    part[12+hb+0] = s0; part[12+hb+1] = s1; part[12+hb+2] = s2;
  }
  part[24 + (hb+0)*128 + lane*2 + 0] = a2d0[0];
  part[24 + (hb+0)*128 + lane*2 + 1] = a2d0[1];
  part[24 + (hb+1)*128 + lane*2 + 0] = a2d1[0];
  part[24 + (hb+1)*128 + lane*2 + 1] = a2d1[1];
  part[24 + (hb+2)*128 + lane*2 + 0] = a2d2[0];
  part[24 + (hb+2)*128 + lane*2 + 1] = a2d2[1];
  {
    int dst0 = (idx0 < 16) ? 1560 + (hb+hh0)*16 + idx0
                           : 1752 + (hb+hh0)*24 + (idx0-16);
    part[dst0] = accV0;
  }
  if (has1) {
    int dst1 = (idx1 < 16) ? 1560 + (hb+hh1)*16 + idx1
                           : 1752 + (hb+hh1)*24 + (idx1-16);
    part[dst1] = accV1;
  }
}

// ---------------- K_comb: combine 4 chunks, normalize, epilogue -------------
__global__ __launch_bounds__(256) void k_comb(float* __restrict__ ws) {
  int i = blockIdx.x, t = threadIdx.x;
  __shared__ float coef[4][12];
  __shared__ float respt[288];
  const float* P = ws + OFF_PARTIAL + (size_t)i*4*2048;
  if (t < 12) {
    float ma = P[t], mb = P[2048+t], mc = P[4096+t], md = P[6144+t];
    float M = fmaxf(fmaxf(ma,mb), fmaxf(mc,md));
    float ea = __expf(ma-M), eb = __expf(mb-M), ec = __expf(mc-M), ed = __expf(md-M);
    float S = P[12+t]*ea + P[2048+12+t]*eb + P[4096+12+t]*ec + P[6144+12+t]*ed;
    float inv = 1.f/S;
    coef[0][t] = ea*inv; coef[1][t] = eb*inv; coef[2][t] = ec*inv; coef[3][t] = ed*inv;
  }
  __syncthreads();
  float* fa = ws + OFF_FA + (size_t)i*2112;
  // att2d (1536)
  for (int r = 0; r < 6; r++) {
    int u = t + r*256;
    int h = u >> 7;
    fa[576+u] = P[24+u]*coef[0][h] + P[2048+24+u]*coef[1][h]
              + P[4096+24+u]*coef[2][h] + P[6144+24+u]*coef[3][h];
  }
  // scalar (192)
  if (t < 192) {
    int h = t >> 4;
    fa[t] = P[1560+t]*coef[0][h] + P[2048+1560+t]*coef[1][h]
          + P[4096+1560+t]*coef[2][h] + P[6144+1560+t]*coef[3][h];
  }
  // points (288) -> respt
  #pragma unroll
  for (int r = 0; r < 2; r++) {
    int u = t + r*256;
    if (u < 288) {
      int h = u / 24;
      respt[u] = P[1752+u]*coef[0][h] + P[2048+1752+u]*coef[1][h]
               + P[4096+1752+u]*coef[2][h] + P[6144+1752+u]*coef[3][h];
    }
  }
  __syncthreads();
  if (t < 96) {
    const float* R  = ws + OFF_R + (size_t)i*12;
    const float* tv = ws + OFF_T + (size_t)i*4;
    float g0 = respt[t*3+0] - tv[0];
    float g1 = respt[t*3+1] - tv[1];
    float g2 = respt[t*3+2] - tv[2];
    float l0 = R[0]*g0 + R[3]*g1 + R[6]*g2;   // R^T * g
    float l1 = R[1]*g0 + R[4]*g1 + R[7]*g2;
    float l2 = R[2]*g0 + R[5]*g1 + R[8]*g2;
    fa[192 + 0*96 + t] = l0;
    fa[192 + 1*96 + t] = l1;
    fa[192 + 2*96 + t] = l2;
    fa[480 + t] = sqrtf(1e-8f + l0*l0 + l1*l1 + l2*l2);
  }
}

// ---------------- K7: final GEMM 768x2112 @ 2112x384, split-K=4 -------------
__global__ __launch_bounds__(256) void k7_gemm(const float* __restrict__ finw,
                                               float* __restrict__ ws) {
  int bi = blockIdx.x, bo = blockIdx.y, bz = blockIdx.z, t = threadIdx.x;
  __shared__ float AsT[16*68];
  __shared__ float Bs[16*68];
  const float* fa = ws + OFF_FA;
  float accv[4][4] = {};
  int i0 = bi*64, o0 = bo*64;
  int ti = t >> 4, to = t & 15;
  for (int kt = 0; kt < 33; kt++) {
    int k0 = bz*528 + kt*16;
    {
      int r = t >> 2, kq = t & 3;
      float4 a = *(const float4*)(fa + (size_t)(i0+r)*2112 + k0 + kq*4);
      AsT[(kq*4+0)*68 + r] = a.x;
      AsT[(kq*4+1)*68 + r] = a.y;
      AsT[(kq*4+2)*68 + r] = a.z;
      AsT[(kq*4+3)*68 + r] = a.w;
      int kr = t >> 4, ol = t & 15;
      *(float4*)&Bs[kr*68 + ol*4] =
          *(const float4*)(finw + (size_t)(k0+kr)*384 + o0 + ol*4);
    }
    __syncthreads();
    for (int k = 0; k < 16; k++) {
      float4 a4 = *(float4*)&AsT[k*68 + ti*4];
      float4 b4 = *(float4*)&Bs[k*68 + to*4];
      accv[0][0] += a4.x*b4.x; accv[0][1] += a4.x*b4.y; accv[0][2] += a4.x*b4.z; accv[0][3] += a4.x*b4.w;
      accv[1][0] += a4.y*b4.x; accv[1][1] += a4.y*b4.y; accv[1][2] += a4.y*b4.z; accv[1][3] += a4.y*b4.w;
      accv[2][0] += a4.z*b4.x; accv[2][1] += a4.z*b4.y; accv[2][2] += a4.z*b4.z; accv[2][3] += a4.z*b4.w;
      accv[3][0] += a4.w*b4.x; accv[3][1] += a4.w*b4.y; accv[3][2] += a4.w*b4.z; accv[3][3] += a4.w*b4.w;
    }
    __syncthreads();
  }
  float* part = ws + OFF_PART + (size_t)bz*768*384;
  #pragma unroll
  for (int ii = 0; ii < 4; ii++) {
    float4 v = make_float4(accv[ii][0], accv[ii][1], accv[ii][2], accv[ii][3]);
    *(float4*)&part[(size_t)(i0 + ti*4 + ii)*384 + o0 + to*4] = v;
  }
}

// ---------------- K8: split-K reduce + bias ---------------------------------
__global__ void k8_out(const float* __restrict__ finb,
                       const float* __restrict__ ws,
                       float* __restrict__ out) {
  int idx = blockIdx.x*256 + threadIdx.x;  // 294912
  int o = idx % 384;
  const float* part = ws + OFF_PART;
  out[idx] = part[idx] + part[294912 + idx] + part[2*294912 + idx]
           + part[3*294912 + idx] + finb[o];
}

// ---------------------------------------------------------------------------
extern "C" void kernel_launch(void* const* d_in, const int* in_sizes, int n_in,
                              void* d_out, int out_size, void* d_ws, size_t ws_size,
                              hipStream_t stream) {
  const float* rec1d = (const float*)d_in[0];
  const float* rep2d = (const float*)d_in[1];
  const float* recT  = (const float*)d_in[2];
  const float* qw    = (const float*)d_in[3];
  const float* qb    = (const float*)d_in[4];
  const float* kvw   = (const float*)d_in[5];
  const float* kvb   = (const float*)d_in[6];
  const float* qpw   = (const float*)d_in[7];
  const float* qpb   = (const float*)d_in[8];
  const float* kvpw  = (const float*)d_in[9];
  const float* kvpb  = (const float*)d_in[10];
  const float* w2dw  = (const float*)d_in[11];
  const float* w2db  = (const float*)d_in[12];
  const float* finw  = (const float*)d_in[13];
  const float* finb  = (const float*)d_in[14];
  const float* tw    = (const float*)d_in[15];
  float* ws  = (float*)d_ws;
  float* out = (float*)d_out;

  hipLaunchKernelGGL(k0_prep, dim3(10), dim3(256), 0, stream, recT, tw, w2dw, ws);
  hipLaunchKernelGGL(k0b_pack, dim3(1733), dim3(256), 0, stream,
                     qw, qb, kvw, kvb, qpw, qpb, kvpw, kvpb, ws);
  hipLaunchKernelGGL(k1_proj, dim3(12, 18), dim3(256), 0, stream, rec1d, ws);
  hipLaunchKernelGGL(k2_frames, dim3(768), dim3(256), 0, stream, ws);
  hipLaunchKernelGGL(k_att2, dim3(4, 768), dim3(256), 0, stream, rep2d, w2db, ws);
  hipLaunchKernelGGL(k_comb, dim3(768), dim3(256), 0, stream, ws);
  hipLaunchKernelGGL(k7_gemm, dim3(12, 6, 4), dim3(256), 0, stream, finw, ws);
  hipLaunchKernelGGL(k8_out, dim3(1152), dim3(256), 0, stream, finb, ws, out);
}